// Round 9
// baseline (2196.093 us; speedup 1.0000x reference)
//
#include <hip/hip_runtime.h>
#include <hip/hip_bf16.h>
#include <cstdint>

// Neural-ODE RK4, v9: v8 dataflow + RING-BUFFERED activations with plain
// (L2-cached) consumer reads and a once-per-16-evals buffer_inv.
// Why safe: (1) every global store in the kernel is sc0 sc1 write-through, so
// L2 never holds dirty lines and buffer_inv can never lose data; (2) yin/h
// live in 16 rotating slots -> within one ring period an address is written
// exactly once, so a cached line can only be stale if it survived from >=16
// evals ago; (3) each block invalidates L2 every 16 evals (at phase-A entry),
// killing anything older than one period; (4) cross-launch staleness is
// handled by the kernel dispatch acquire (and the computation is deterministic
// anyway); (5) 1KB guard gaps between slots fence any next-line prefetch.
// Gain: the 64x-duplicated yin read and 16x-duplicated h read per row-group
// are served by each XCD's L2 (all blocks of an XCD share one row group under
// blockIdx%8 round-robin) instead of hammering L3 16 MB/eval.
// Sync unchanged from v8 (3 hops): fB -> A -> fA -> B(partial) -> fP -> owner.

#define NBLK 256
#define NTHR 256
#define X_   1024
#define H_   4096
#define T_   64
#define NEV  252
#define RING 16
#define YSLOT 132096u   // 128 KB + 1 KB guard
#define HSLOT 525312u   // 512 KB + 1 KB guard

typedef __bf16 bf16_t;
typedef __attribute__((ext_vector_type(8))) __bf16 bf16x8;
typedef __attribute__((ext_vector_type(4))) float  f32x4;
typedef __attribute__((ext_vector_type(2))) uint32_t u32x2;
typedef __attribute__((ext_vector_type(4))) uint32_t u32x4;

// ---- workspace layout (bytes) ----
#define WS_FLAGS 0                            // 512 slots * 64B = 32 KB
#define WS_YIN   32768                        // RING x YSLOT   (2.11 MB)
#define WS_H     (32768 + RING * YSLOT)       // RING x HSLOT   (8.40 MB)
#define WS_P     (WS_H + RING * HSLOT)        // f32 partials   (768 KB)
#define WS_NEED  (WS_P + 786432)
// flag slots (u32 stride 16 = 64B):
//   fA: 0   + mg*64 + g16; fB: 256 + mg*16 + c; fP: 320 + (mg*16+c)*3 + (q-1)

// -------- sc0 sc1 write-through stores (L2 never dirty) --------------------
__device__ inline void store_coh_b16(bf16_t* p, float v) {
  uint32_t d = (uint32_t)__builtin_bit_cast(uint16_t, (bf16_t)v);
  asm volatile("global_store_short %0, %1, off sc0 sc1" :: "v"(p), "v"(d) : "memory");
}
__device__ inline void store_coh_f32(float* p, float v) {
  asm volatile("global_store_dword %0, %1, off sc0 sc1" :: "v"(p), "v"(v) : "memory");
}
__device__ inline void store_coh_b64(bf16_t* p, u32x2 v) {
  asm volatile("global_store_dwordx2 %0, %1, off sc0 sc1" :: "v"(p), "v"(v) : "memory");
}
__device__ inline void store_coh_f32x4(float* p, f32x4 v) {
  asm volatile("global_store_dwordx4 %0, %1, off sc0 sc1" :: "v"(p), "v"(v) : "memory");
}
__device__ inline void store_flag(uint32_t* p, uint32_t v) {
  asm volatile("global_store_dword %0, %1, off sc0 sc1" :: "v"(p), "v"(v) : "memory");
}
__device__ inline uint32_t load_flag(const uint32_t* p) {
  uint32_t v;
  asm volatile("global_load_dword %0, %1, off sc0 sc1\n\ts_waitcnt vmcnt(0)"
               : "=v"(v) : "v"(p) : "memory");
  return v;
}
__device__ inline void load3_coh(const float* p0, const float* p1, const float* p2,
                                 f32x4& a, f32x4& b, f32x4& c) {
  asm volatile(
      "global_load_dwordx4 %0, %3, off sc0 sc1\n\t"
      "global_load_dwordx4 %1, %4, off sc0 sc1\n\t"
      "global_load_dwordx4 %2, %5, off sc0 sc1\n\t"
      "s_waitcnt vmcnt(0)"
      : "=&v"(a), "=&v"(b), "=&v"(c)
      : "v"(p0), "v"(p1), "v"(p2) : "memory");
}
__device__ inline uint32_t pkbf(float a, float b) {
  return (uint32_t)__builtin_bit_cast(uint16_t, (bf16_t)a)
       | ((uint32_t)__builtin_bit_cast(uint16_t, (bf16_t)b) << 16);
}

// plain (L2-cached) data loads — safety comes from the ring + periodic inv
#define LDGP(dst, P, OFF) \
  asm volatile("global_load_dwordx4 %0, %1, off offset:" OFF \
               : "=v"(dst) : "v"(P))
#define DECL8(P) u32x4 P##0, P##1, P##2, P##3, P##4, P##5, P##6, P##7
#define LD8P(P, PTR) \
  LDGP(P##0, PTR, "0");   LDGP(P##1, PTR, "64");  LDGP(P##2, PTR, "128"); \
  LDGP(P##3, PTR, "192"); LDGP(P##4, PTR, "256"); LDGP(P##5, PTR, "320"); \
  LDGP(P##6, PTR, "384"); LDGP(P##7, PTR, "448")
#define WAITV0 do { asm volatile("s_waitcnt vmcnt(0)" ::: "memory"); \
  __builtin_amdgcn_sched_barrier(0); } while (0)
#define BC(q) __builtin_bit_cast(bf16x8, q)

#define POLL(SLOTEXPR, NLANES, TARGET) do { \
  if (w == 0 && l < (NLANES)) { \
    uint32_t* _p = flags + (SLOTEXPR) * 16; \
    uint32_t _v = load_flag(_p); \
    while (_v < (TARGET)) { __builtin_amdgcn_s_sleep(1); _v = load_flag(_p); } \
  } \
  __syncthreads(); \
  __builtin_amdgcn_sched_barrier(0); \
} while (0)

__global__ void __launch_bounds__(NTHR, 1) node_rk4_kernel(
    const float* __restrict__ x, const float* __restrict__ ts,
    const float* __restrict__ W1, const float* __restrict__ b1,
    const float* __restrict__ W2, const float* __restrict__ b2,
    float* __restrict__ out, uint8_t* __restrict__ ws)
{
  uint32_t* flags = (uint32_t*)(ws + WS_FLAGS);
  float*    pbuf  = (float*)(ws + WS_P);

  const int tid = threadIdx.x;
  const int b   = blockIdx.x;
  const int w   = tid >> 6;    // wave 0..3
  const int l   = tid & 63;
  const int lr  = l & 15;
  const int lh  = l >> 4;
  const int g16 = b >> 2;      // 0..63
  const int mg  = b & 3;       // row group (independent solve), rows [16mg,+16)
  const int c   = g16 & 15;    // B-role: out-col group [64c,+64)
  const int q   = g16 >> 4;    // B-role: K-chunk [1024q,+1024); q==0 owns RK4

  __shared__ float red[4][4][4][64];   // [writer-wave][ct][r][lane] — stride-4B, conflict-free
  __shared__ float tr[4][64][4];       // per-wave transpose scratch
  __shared__ float tsl[T_];
  if (tid < T_) tsl[tid] = ts[tid];

  // ---- pack W1/W2 B-fragments (waves split K into 256-chunks) ----
  bf16x8 w1f[4][8], w2f[4][8];
  #pragma unroll
  for (int ct = 0; ct < 4; ct++)
    #pragma unroll
    for (int ks = 0; ks < 8; ks++)
      #pragma unroll
      for (int j = 0; j < 8; j++) {
        w1f[ct][ks][j] = (bf16_t)W1[(size_t)(w*256 + ks*32 + lh*8 + j) * H_ + g16*64 + ct*16 + lr];
        w2f[ct][ks][j] = (bf16_t)W2[(size_t)(q*1024 + w*256 + ks*32 + lh*8 + j) * X_ + c*64 + ct*16 + lr];
      }

  const float bias1 = b1[g16*64 + w*16 + lr];
  const float bias2 = b2[c*64 + w*16 + lr];

  // ---- RK4 state (owners only): row = mg*16 + lh*4 + r, col = c*64 + w*16 + lr
  f32x4 y = {0.f,0.f,0.f,0.f}, yac = {0.f,0.f,0.f,0.f};
  if (q == 0) {
    bf16_t* yslot0 = (bf16_t*)(ws + WS_YIN);             // eval 0 reads slot 0
    #pragma unroll
    for (int r = 0; r < 4; r++) {
      const int row = mg*16 + lh*4 + r, col = c*64 + w*16 + lr;
      y[r] = x[(size_t)row * X_ + col];
      store_coh_f32(&out[(size_t)row * (T_ * X_) + col], y[r]);  // pred[:,0,:]
      store_coh_b16(yslot0 + (size_t)row * X_ + col, y[r]);
    }
    asm volatile("s_waitcnt vmcnt(0)" ::: "memory");
    __syncthreads();
    if (tid == 0) store_flag(flags + (256 + mg*16 + c) * 16, 1u);
  }

  for (int n = 0; n < NEV; n++) {
    const uint32_t e = (uint32_t)n + 1u;
    const int step = n >> 2, ev = n & 3;
    const float dt  = tsl[step + 1] - tsl[step];
    const float dth = 0.5f * dt, dt6 = dt * (1.f / 6.f), dt3 = dt * (1.f / 3.f);

    bf16_t* yin_rd = (bf16_t*)(ws + WS_YIN + (size_t)(n % RING) * YSLOT);
    bf16_t* yin_wr = (bf16_t*)(ws + WS_YIN + (size_t)((n + 1) % RING) * YSLOT);
    bf16_t* hbuf   = (bf16_t*)(ws + WS_H   + (size_t)(n % RING) * HSLOT);

    // ===== phase A: wait 16 owner fB flags; h tile = tanh(yin @ W1 + b1) =====
    POLL(256 + mg*16 + l, 16, e);
    if ((n & (RING - 1)) == 0) {   // once per ring period: drop lines >= 1 period old
      asm volatile("buffer_inv sc0 sc1\n\ts_waitcnt vmcnt(0)" ::: "memory");
      __builtin_amdgcn_sched_barrier(0);
    }
    {
      bf16x8 af[8];
      {
        DECL8(qa);
        const bf16_t* ap = yin_rd + (size_t)(mg*16 + lr) * X_ + w*256 + lh*8;
        LD8P(qa, ap);
        WAITV0;
        af[0]=BC(qa0); af[1]=BC(qa1); af[2]=BC(qa2); af[3]=BC(qa3);
        af[4]=BC(qa4); af[5]=BC(qa5); af[6]=BC(qa6); af[7]=BC(qa7);
      }
      #pragma unroll
      for (int ct = 0; ct < 4; ct++) {
        f32x4 a = {0.f,0.f,0.f,0.f};
        #pragma unroll
        for (int ks = 0; ks < 8; ks++)
          a = __builtin_amdgcn_mfma_f32_16x16x32_bf16(af[ks], w1f[ct][ks], a, 0, 0, 0);
        #pragma unroll
        for (int r = 0; r < 4; r++) red[w][ct][r][l] = a[r];
      }
      __syncthreads();
      f32x4 h4;
      #pragma unroll
      for (int r = 0; r < 4; r++)
        h4[r] = tanhf(red[0][w][r][l] + red[1][w][r][l] + red[2][w][r][l] + red[3][w][r][l] + bias1);
      *(f32x4*)&tr[w][l][0] = h4;
      const int trow = l >> 2, tc0 = (l & 3) * 4;
      float v0 = tr[w][(trow >> 2) * 16 + tc0 + 0][trow & 3];
      float v1 = tr[w][(trow >> 2) * 16 + tc0 + 1][trow & 3];
      float v2 = tr[w][(trow >> 2) * 16 + tc0 + 2][trow & 3];
      float v3 = tr[w][(trow >> 2) * 16 + tc0 + 3][trow & 3];
      u32x2 pk; pk[0] = pkbf(v0, v1); pk[1] = pkbf(v2, v3);
      store_coh_b64(hbuf + (size_t)(mg*16 + trow) * H_ + g16*64 + w*16 + tc0, pk);
    }
    asm volatile("s_waitcnt vmcnt(0)" ::: "memory");
    __syncthreads();
    if (tid == 0) store_flag(flags + (mg*64 + g16) * 16, e);

    // ===== phase B: wait 16 fA flags of my K-chunk; partial = h @ W2chunk =====
    POLL(mg*64 + q*16 + l, 16, e);
    f32x4 p4;
    {
      bf16x8 bfr[8];
      {
        DECL8(qb);
        const bf16_t* bp = hbuf + (size_t)(mg*16 + lr) * H_ + q*1024 + w*256 + lh*8;
        LD8P(qb, bp);
        WAITV0;
        bfr[0]=BC(qb0); bfr[1]=BC(qb1); bfr[2]=BC(qb2); bfr[3]=BC(qb3);
        bfr[4]=BC(qb4); bfr[5]=BC(qb5); bfr[6]=BC(qb6); bfr[7]=BC(qb7);
      }
      #pragma unroll
      for (int ct = 0; ct < 4; ct++) {
        f32x4 a = {0.f,0.f,0.f,0.f};
        #pragma unroll
        for (int ks = 0; ks < 8; ks++)
          a = __builtin_amdgcn_mfma_f32_16x16x32_bf16(bfr[ks], w2f[ct][ks], a, 0, 0, 0);
        #pragma unroll
        for (int r = 0; r < 4; r++) red[w][ct][r][l] = a[r];
      }
      __syncthreads();
      #pragma unroll
      for (int r = 0; r < 4; r++)
        p4[r] = red[0][w][r][l] + red[1][w][r][l] + red[2][w][r][l] + red[3][w][r][l];
    }

    if (q != 0) {
      // peer: publish fp32 partial, flag fP
      float* ps = pbuf + ((size_t)(mg*16 + c) * 3 + (q - 1)) * 1024 + w*256 + l*4;
      store_coh_f32x4(ps, p4);
      asm volatile("s_waitcnt vmcnt(0)" ::: "memory");
      __syncthreads();
      if (tid == 0) store_flag(flags + (320 + (mg*16 + c) * 3 + (q - 1)) * 16, e);
    } else {
      // owner: wait 3 peer partials, sum, RK4, publish yin (next ring slot)
      POLL(320 + (mg*16 + c) * 3 + l, 3, e);
      const float* pb = pbuf + (size_t)(mg*16 + c) * 3 * 1024 + w*256 + l*4;
      f32x4 pa_, pb_, pc_;
      load3_coh(pb, pb + 1024, pb + 2048, pa_, pb_, pc_);
      #pragma unroll
      for (int r = 0; r < 4; r++) {
        const float kv = p4[r] + pa_[r] + pb_[r] + pc_[r] + bias2;
        float ypub;
        if (ev == 0)      { yac[r] = y[r] + dt6 * kv; ypub = y[r] + dth * kv; }
        else if (ev == 1) { yac[r] += dt3 * kv;       ypub = y[r] + dth * kv; }
        else if (ev == 2) { yac[r] += dt3 * kv;       ypub = y[r] + dt * kv;  }
        else              { y[r] = yac[r] + dt6 * kv; ypub = y[r]; }
        const int row = mg*16 + lh*4 + r, col = c*64 + w*16 + lr;
        store_coh_b16(yin_wr + (size_t)row * X_ + col, ypub);
        if (ev == 3)
          store_coh_f32(&out[(size_t)row * (T_ * X_) + (size_t)(step + 1) * X_ + col], y[r]);
      }
      asm volatile("s_waitcnt vmcnt(0)" ::: "memory");
      __syncthreads();
      if (tid == 0) store_flag(flags + (256 + mg*16 + c) * 16, e + 1u);
    }
  }
}

extern "C" void kernel_launch(void* const* d_in, const int* in_sizes, int n_in,
                              void* d_out, int out_size, void* d_ws, size_t ws_size,
                              hipStream_t stream) {
  const float* x  = (const float*)d_in[0];
  const float* ts = (const float*)d_in[1];
  const float* W1 = (const float*)d_in[2];
  const float* b1 = (const float*)d_in[3];
  const float* W2 = (const float*)d_in[4];
  const float* b2 = (const float*)d_in[5];
  float* out = (float*)d_out;
  uint8_t* ws = (uint8_t*)d_ws;
  if (ws_size < (size_t)WS_NEED) return;
  hipMemsetAsync(d_ws, 0, 32768, stream);  // reset all flag lines every launch

  void* args[] = {(void*)&x, (void*)&ts, (void*)&W1, (void*)&b1,
                  (void*)&W2, (void*)&b2, (void*)&out, (void*)&ws};
  hipError_t err = hipLaunchCooperativeKernel((void*)node_rk4_kernel,
                                              dim3(NBLK), dim3(NTHR), args, 0, stream);
  if (err != hipSuccess) {
    node_rk4_kernel<<<dim3(NBLK), dim3(NTHR), 0, stream>>>(x, ts, W1, b1, W2, b2, out, ws);
  }
}

// Round 13
// 2061.760 us; speedup vs baseline: 1.0652x; 1.0652x over previous
//
#include <hip/hip_runtime.h>
#include <hip/hip_bf16.h>
#include <cstdint>

// Neural-ODE RK4, v13 = v8 (proven 2084us) + two surgical trims.
// v10-v12 post-mortem: the zero-flag poll-data-directly family fails on HW
// (consumers can permanently miss a unit's update when spinning sc0sc1 loads
// on an address being concurrently written). The flag-then-data protocol
// (v6/v8/v9) is proven incl. graph-replay revalidation -> rebuild on v8.
// Trims vs v8:
//  (1) per-wave narrow polls: phase-A wave w polls only owners 4w..4w+3
//      (its yin cols [256w,+256)); phase-B wave w polls only A-producers
//      16q+4w..+3; owner-partial poll done by lanes 0..2 of every wave.
//      No post-poll __syncthreads — each wave starts its GEMM when ITS
//      producers landed. Flag PUBLISHES remain block-level (drain + barrier
//      + tid0 store), so the v8 WAR proof is unchanged (poll-set unions are
//      identical to v8's coverage).
//  (2) conflict-free reduce layout red[4][4][4][64] (from v9, proven):
//      lane-stride 4B -> SQ_LDS_BANK_CONFLICT ~3.1e7 -> ~6e6.
// Roles as v8: block b: g16=b>>2, mg=b&3 (row group), c=g16&15, q=g16>>4
// (B: out-cols [64c,+64), K-chunk q; q==0 owns RK4 state). Weights in VGPRs.

#define NBLK 256
#define NTHR 256
#define X_   1024
#define H_   4096
#define T_   64
#define NEV  252

typedef __bf16 bf16_t;
typedef __attribute__((ext_vector_type(8))) __bf16 bf16x8;
typedef __attribute__((ext_vector_type(4))) float  f32x4;
typedef __attribute__((ext_vector_type(2))) uint32_t u32x2;
typedef __attribute__((ext_vector_type(4))) uint32_t u32x4;

// ---- workspace layout (bytes) ----
#define WS_FLAGS 0                            // 512 slots * 64B = 32 KB
#define WS_YIN   32768                        // bf16 [64][1024]   (128 KB)
#define WS_H     (32768 + 131072)             // bf16 [64][4096]   (512 KB)
#define WS_P     (32768 + 131072 + 524288)    // f32 partials      (768 KB)
#define WS_NEED  (WS_P + 786432)
// flag slots (u32 stride 16 = 64 B apart):
//   fA: 0   + mg*64 + g16          (A published h cols [64g16,+64), eval e)
//   fB: 256 + mg*16 + c            (owner published yin cols [64c,+64), eval e)
//   fP: 320 + (mg*16+c)*3 + (q-1)  (peer q published partial, eval e)

// -------- coherent ops (cross-block data at the L3 coherence point) --------
__device__ inline void store_coh_b16(bf16_t* p, float v) {
  uint32_t d = (uint32_t)__builtin_bit_cast(uint16_t, (bf16_t)v);
  asm volatile("global_store_short %0, %1, off sc0 sc1" :: "v"(p), "v"(d) : "memory");
}
__device__ inline void store_coh_f32(float* p, float v) {
  asm volatile("global_store_dword %0, %1, off sc0 sc1" :: "v"(p), "v"(v) : "memory");
}
__device__ inline void store_coh_b64(bf16_t* p, u32x2 v) {
  asm volatile("global_store_dwordx2 %0, %1, off sc0 sc1" :: "v"(p), "v"(v) : "memory");
}
__device__ inline void store_coh_f32x4(float* p, f32x4 v) {
  asm volatile("global_store_dwordx4 %0, %1, off sc0 sc1" :: "v"(p), "v"(v) : "memory");
}
__device__ inline void store_flag(uint32_t* p, uint32_t v) {
  asm volatile("global_store_dword %0, %1, off sc0 sc1" :: "v"(p), "v"(v) : "memory");
}
__device__ inline uint32_t load_flag(const uint32_t* p) {
  uint32_t v;
  asm volatile("global_load_dword %0, %1, off sc0 sc1\n\ts_waitcnt vmcnt(0)"
               : "=v"(v) : "v"(p) : "memory");
  return v;
}
__device__ inline void load3_coh(const float* p0, const float* p1, const float* p2,
                                 f32x4& a, f32x4& b, f32x4& c) {
  asm volatile(
      "global_load_dwordx4 %0, %3, off sc0 sc1\n\t"
      "global_load_dwordx4 %1, %4, off sc0 sc1\n\t"
      "global_load_dwordx4 %2, %5, off sc0 sc1\n\t"
      "s_waitcnt vmcnt(0)"
      : "=&v"(a), "=&v"(b), "=&v"(c)
      : "v"(p0), "v"(p1), "v"(p2) : "memory");
}
__device__ inline uint32_t pkbf(float a, float b) {
  return (uint32_t)__builtin_bit_cast(uint16_t, (bf16_t)a)
       | ((uint32_t)__builtin_bit_cast(uint16_t, (bf16_t)b) << 16);
}

#define LDG(dst, P, OFF) \
  asm volatile("global_load_dwordx4 %0, %1, off offset:" OFF " sc0 sc1" \
               : "=v"(dst) : "v"(P))
#define DECL8(P) u32x4 P##0, P##1, P##2, P##3, P##4, P##5, P##6, P##7
#define LD8(P, PTR) \
  LDG(P##0, PTR, "0");   LDG(P##1, PTR, "64");  LDG(P##2, PTR, "128"); \
  LDG(P##3, PTR, "192"); LDG(P##4, PTR, "256"); LDG(P##5, PTR, "320"); \
  LDG(P##6, PTR, "384"); LDG(P##7, PTR, "448")
#define WAITV0 do { asm volatile("s_waitcnt vmcnt(0)" ::: "memory"); \
  __builtin_amdgcn_sched_barrier(0); } while (0)
#define BC(q) __builtin_bit_cast(bf16x8, q)

// per-wave narrow poll: lanes l < NL of EVERY wave spin on flags SLOT(l);
// the wave reconverges at loop exit — no block barrier.
#define PWPOLL(SLOTEXPR, NL, TARGET) do { \
  if (l < (NL)) { \
    uint32_t* _p = flags + (SLOTEXPR) * 16; \
    uint32_t _v = load_flag(_p); \
    while (_v < (TARGET)) { __builtin_amdgcn_s_sleep(1); _v = load_flag(_p); } \
  } \
  __builtin_amdgcn_sched_barrier(0); \
} while (0)

__global__ void __launch_bounds__(NTHR, 1) node_rk4_kernel(
    const float* __restrict__ x, const float* __restrict__ ts,
    const float* __restrict__ W1, const float* __restrict__ b1,
    const float* __restrict__ W2, const float* __restrict__ b2,
    float* __restrict__ out, uint8_t* __restrict__ ws)
{
  uint32_t* flags = (uint32_t*)(ws + WS_FLAGS);
  bf16_t* yin  = (bf16_t*)(ws + WS_YIN);
  bf16_t* hbuf = (bf16_t*)(ws + WS_H);
  float*  pbuf = (float*)(ws + WS_P);

  const int tid = threadIdx.x;
  const int b   = blockIdx.x;
  const int w   = tid >> 6;    // wave 0..3
  const int l   = tid & 63;
  const int lr  = l & 15;
  const int lh  = l >> 4;
  const int g16 = b >> 2;      // 0..63
  const int mg  = b & 3;       // row group (independent solve), rows [16mg,+16)
  const int c   = g16 & 15;    // B-role: out-col group [64c,+64)
  const int q   = g16 >> 4;    // B-role: K-chunk [1024q,+1024); q==0 owns RK4

  __shared__ float red[4][4][4][64];   // [wave][ct][r][lane] — stride-4B, conflict-free
  __shared__ float tr[4][64][4];       // per-wave transpose scratch
  __shared__ float tsl[T_];
  if (tid < T_) tsl[tid] = ts[tid];

  // ---- pack W1/W2 B-fragments (waves split K into 256-chunks), as v8 ----
  bf16x8 w1f[4][8], w2f[4][8];
  #pragma unroll
  for (int ct = 0; ct < 4; ct++)
    #pragma unroll
    for (int ks = 0; ks < 8; ks++)
      #pragma unroll
      for (int j = 0; j < 8; j++) {
        w1f[ct][ks][j] = (bf16_t)W1[(size_t)(w*256 + ks*32 + lh*8 + j) * H_ + g16*64 + ct*16 + lr];
        w2f[ct][ks][j] = (bf16_t)W2[(size_t)(q*1024 + w*256 + ks*32 + lh*8 + j) * X_ + c*64 + ct*16 + lr];
      }

  const float bias1 = b1[g16*64 + w*16 + lr];   // A epilogue: wave w owns ct==w
  const float bias2 = b2[c*64 + w*16 + lr];     // B owner: wave w owns ct==w

  // ---- RK4 state (owners only): row = mg*16 + lh*4 + r, col = c*64 + w*16 + lr
  f32x4 y = {0.f,0.f,0.f,0.f}, yac = {0.f,0.f,0.f,0.f};
  if (q == 0) {
    #pragma unroll
    for (int r = 0; r < 4; r++) {
      const int row = mg*16 + lh*4 + r, col = c*64 + w*16 + lr;
      y[r] = x[(size_t)row * X_ + col];
      store_coh_f32(&out[(size_t)row * (T_ * X_) + col], y[r]);  // pred[:,0,:]
      store_coh_b16(yin + (size_t)row * X_ + col, y[r]);
    }
    asm volatile("s_waitcnt vmcnt(0)" ::: "memory");
    __syncthreads();
    if (tid == 0) store_flag(flags + (256 + mg*16 + c) * 16, 1u);
  }

  for (int n = 0; n < NEV; n++) {
    const uint32_t e = (uint32_t)n + 1u;
    const int step = n >> 2, ev = n & 3;
    const float dt  = tsl[step + 1] - tsl[step];
    const float dth = 0.5f * dt, dt6 = dt * (1.f / 6.f), dt3 = dt * (1.f / 3.f);

    // ===== phase A: wave w waits ITS 4 owners (cols [256w,+256)); then
    //       h tile = tanh(yin @ W1 + b1) =====
    PWPOLL(256 + mg*16 + 4*w + l, 4, e);
    {
      bf16x8 af[8];
      {
        DECL8(qa);
        const bf16_t* ap = yin + (size_t)(mg*16 + lr) * X_ + w*256 + lh*8;
        LD8(qa, ap);
        WAITV0;
        af[0]=BC(qa0); af[1]=BC(qa1); af[2]=BC(qa2); af[3]=BC(qa3);
        af[4]=BC(qa4); af[5]=BC(qa5); af[6]=BC(qa6); af[7]=BC(qa7);
      }
      #pragma unroll
      for (int ct = 0; ct < 4; ct++) {
        f32x4 a = {0.f,0.f,0.f,0.f};
        #pragma unroll
        for (int ks = 0; ks < 8; ks++)
          a = __builtin_amdgcn_mfma_f32_16x16x32_bf16(af[ks], w1f[ct][ks], a, 0, 0, 0);
        #pragma unroll
        for (int r = 0; r < 4; r++) red[w][ct][r][l] = a[r];
      }
      __syncthreads();
      f32x4 h4;
      #pragma unroll
      for (int r = 0; r < 4; r++)
        h4[r] = tanhf(red[0][w][r][l] + red[1][w][r][l] + red[2][w][r][l] + red[3][w][r][l] + bias1);
      *(f32x4*)&tr[w][l][0] = h4;
      const int trow = l >> 2, tc0 = (l & 3) * 4;
      float v0 = tr[w][(trow >> 2) * 16 + tc0 + 0][trow & 3];
      float v1 = tr[w][(trow >> 2) * 16 + tc0 + 1][trow & 3];
      float v2 = tr[w][(trow >> 2) * 16 + tc0 + 2][trow & 3];
      float v3 = tr[w][(trow >> 2) * 16 + tc0 + 3][trow & 3];
      u32x2 pk; pk[0] = pkbf(v0, v1); pk[1] = pkbf(v2, v3);
      store_coh_b64(hbuf + (size_t)(mg*16 + trow) * H_ + g16*64 + w*16 + tc0, pk);
    }
    asm volatile("s_waitcnt vmcnt(0)" ::: "memory");
    __syncthreads();
    if (tid == 0) store_flag(flags + (mg*64 + g16) * 16, e);

    // ===== phase B: wave w waits ITS 4 A-producers (h cols q*1024+[256w,+256));
    //       partial = h @ W2chunk =====
    PWPOLL(mg*64 + q*16 + 4*w + l, 4, e);
    f32x4 p4;
    {
      bf16x8 bfr[8];
      {
        DECL8(qb);
        const bf16_t* bp = hbuf + (size_t)(mg*16 + lr) * H_ + q*1024 + w*256 + lh*8;
        LD8(qb, bp);
        WAITV0;
        bfr[0]=BC(qb0); bfr[1]=BC(qb1); bfr[2]=BC(qb2); bfr[3]=BC(qb3);
        bfr[4]=BC(qb4); bfr[5]=BC(qb5); bfr[6]=BC(qb6); bfr[7]=BC(qb7);
      }
      #pragma unroll
      for (int ct = 0; ct < 4; ct++) {
        f32x4 a = {0.f,0.f,0.f,0.f};
        #pragma unroll
        for (int ks = 0; ks < 8; ks++)
          a = __builtin_amdgcn_mfma_f32_16x16x32_bf16(bfr[ks], w2f[ct][ks], a, 0, 0, 0);
        #pragma unroll
        for (int r = 0; r < 4; r++) red[w][ct][r][l] = a[r];
      }
      __syncthreads();
      #pragma unroll
      for (int r = 0; r < 4; r++)
        p4[r] = red[0][w][r][l] + red[1][w][r][l] + red[2][w][r][l] + red[3][w][r][l];
    }

    if (q != 0) {
      // peer: publish fp32 partial, then flag fP (block-level release)
      float* ps = pbuf + ((size_t)(mg*16 + c) * 3 + (q - 1)) * 1024 + w*256 + l*4;
      store_coh_f32x4(ps, p4);
      asm volatile("s_waitcnt vmcnt(0)" ::: "memory");
      __syncthreads();
      if (tid == 0) store_flag(flags + (320 + (mg*16 + c) * 3 + (q - 1)) * 16, e);
    } else {
      // owner: every wave polls the 3 peer flags (lanes 0..2), then loads
      // partials (flag-then-data), sums, RK4, publishes yin(e+1)
      PWPOLL(320 + (mg*16 + c) * 3 + l, 3, e);
      const float* pb = pbuf + (size_t)(mg*16 + c) * 3 * 1024 + w*256 + l*4;
      f32x4 pa_, pb_, pc_;
      load3_coh(pb, pb + 1024, pb + 2048, pa_, pb_, pc_);
      #pragma unroll
      for (int r = 0; r < 4; r++) {
        const float kv = p4[r] + pa_[r] + pb_[r] + pc_[r] + bias2;
        float ypub;
        if (ev == 0)      { yac[r] = y[r] + dt6 * kv; ypub = y[r] + dth * kv; }
        else if (ev == 1) { yac[r] += dt3 * kv;       ypub = y[r] + dth * kv; }
        else if (ev == 2) { yac[r] += dt3 * kv;       ypub = y[r] + dt * kv;  }
        else              { y[r] = yac[r] + dt6 * kv; ypub = y[r]; }
        const int row = mg*16 + lh*4 + r, col = c*64 + w*16 + lr;
        store_coh_b16(yin + (size_t)row * X_ + col, ypub);
        if (ev == 3)
          store_coh_f32(&out[(size_t)row * (T_ * X_) + (size_t)(step + 1) * X_ + col], y[r]);
      }
      asm volatile("s_waitcnt vmcnt(0)" ::: "memory");
      __syncthreads();
      if (tid == 0) store_flag(flags + (256 + mg*16 + c) * 16, e + 1u);
    }
  }
}

extern "C" void kernel_launch(void* const* d_in, const int* in_sizes, int n_in,
                              void* d_out, int out_size, void* d_ws, size_t ws_size,
                              hipStream_t stream) {
  const float* x  = (const float*)d_in[0];
  const float* ts = (const float*)d_in[1];
  const float* W1 = (const float*)d_in[2];
  const float* b1 = (const float*)d_in[3];
  const float* W2 = (const float*)d_in[4];
  const float* b2 = (const float*)d_in[5];
  float* out = (float*)d_out;
  uint8_t* ws = (uint8_t*)d_ws;
  if (ws_size < (size_t)WS_NEED) return;
  hipMemsetAsync(d_ws, 0, 32768, stream);  // reset all flag lines every launch

  void* args[] = {(void*)&x, (void*)&ts, (void*)&W1, (void*)&b1,
                  (void*)&W2, (void*)&b2, (void*)&out, (void*)&ws};
  hipError_t err = hipLaunchCooperativeKernel((void*)node_rk4_kernel,
                                              dim3(NBLK), dim3(NTHR), args, 0, stream);
  if (err != hipSuccess) {
    node_rk4_kernel<<<dim3(NBLK), dim3(NTHR), 0, stream>>>(x, ts, W1, b1, W2, b2, out, ws);
  }
}